// Round 5
// baseline (53.850 us; speedup 1.0000x reference)
//
#include <hip/hip_runtime.h>
#include <stdint.h>

typedef __attribute__((ext_vector_type(8))) short short8;
typedef __attribute__((ext_vector_type(4))) float f32x4;

#define DEVI __device__ __forceinline__

DEVI ushort f2bf(float f) {
  union { float f; uint32_t u; } v; v.f = f;
  uint32_t r = v.u + 0x7fffu + ((v.u >> 16) & 1u);
  return (ushort)(r >> 16);
}

// ---------------------------------------------------------------------------
// Quantum sim collapses analytically (params provably dead):
//   feats per 2x2 patch = [cos v0, cos v1, cos v0*cos v2, cos v1*cos v3].
// Blocks [0,6656): feats bf16 (padded 784->832), every cos done exactly once.
// Blocks [6656,7616): cast W1 (pad->832) and W2 to bf16, exactly once.
// ---------------------------------------------------------------------------
__global__ __launch_bounds__(256) void feats_prep_kernel(
    const float* __restrict__ x, ushort* __restrict__ feats,
    const float* __restrict__ W1, const float* __restrict__ W2,
    ushort* __restrict__ w1b, ushort* __restrict__ w2b) {
  int b = blockIdx.x;
  if (b < 6656) {
    int t = b * 256 + threadIdx.x;   // 8192 * 208 items
    int row = t / 208;
    int q = t - row * 208;
    if (q < 196) {
      int i = q / 14, j = q - i * 14;
      const float* px = x + (size_t)row * 784 + i * 56 + j * 2;
      float2 top = *(const float2*)px;
      float2 bot = *(const float2*)(px + 28);
      float c0 = __cosf(top.x), c1 = __cosf(top.y);
      float c2 = __cosf(bot.x), c3 = __cosf(bot.y);
      ushort4 o;
      o.x = f2bf(c0); o.y = f2bf(c1); o.z = f2bf(c0 * c2); o.w = f2bf(c1 * c3);
      *(ushort4*)(feats + (size_t)row * 832 + q * 4) = o;
    } else {
      ushort4 z; z.x = 0; z.y = 0; z.z = 0; z.w = 0;
      *(ushort4*)(feats + (size_t)row * 832 + 784 + (q - 196) * 4) = z;
    }
  } else {
    int t = (b - 6656) * 256 + threadIdx.x;   // 256*832 + 128*256 = 245760
    if (t < 256 * 832) {
      int r = t / 832, c = t - r * 832;
      w1b[t] = (c < 784) ? f2bf(W1[r * 784 + c]) : (ushort)0;
    } else {
      int u = t - 256 * 832;
      w2b[u] = f2bf(W2[u]);
    }
  }
}

// ---------------------------------------------------------------------------
// Pure-bf16 double-buffered GEMM: C = relu(A @ W^T + bias), fp32 acc.
// Per K-step/thread: 4 coalesced uint4 loads + 4 ds_write_b128 +
// 8 ds_read_b128 + 8 MFMA  (staging:MFMA ~1:1, vs 10:1 in round 4's fusion).
// LDA=72 (144B stride) -> <=2-way LDS aliasing (free).
// ---------------------------------------------------------------------------
template <int BM, int BN, int BK, int M, int N, int K, bool RELU>
__global__ __launch_bounds__(256) void gemm_bt_db(
    const ushort* __restrict__ A, const ushort* __restrict__ W,
    const float* __restrict__ bias, ushort* __restrict__ C) {
  constexpr int MF = BM / 32;
  constexpr int NF = BN / 32;
  constexpr int LDA = BK + 8;
  constexpr int SLOTS = BK / 8;
  constexpr int A_IT = BM * SLOTS / 256;
  constexpr int B_IT = BN * SLOTS / 256;
  constexpr int NK = K / BK;
  constexpr int MT = M / BM;

  __shared__ ushort As[2][BM * LDA];
  __shared__ ushort Bs[2][BN * LDA];

  const int bm = blockIdx.x % MT;
  const int bn = blockIdx.x / MT;
  const int m0 = bm * BM, n0 = bn * BN;

  const int tid = threadIdx.x;
  const int lane = tid & 63;
  const int w = tid >> 6, wm = w >> 1, wn = w & 1;

  uint4 av[A_IT], bv[B_IT];

  auto loadT = [&](int kt) {
    const int k0 = kt * BK;
#pragma unroll
    for (int c = 0; c < A_IT; ++c) {
      int flat = c * 256 + tid, r = flat / SLOTS, s = flat % SLOTS;
      av[c] = *(const uint4*)(A + (size_t)(m0 + r) * K + k0 + s * 8);
    }
#pragma unroll
    for (int c = 0; c < B_IT; ++c) {
      int flat = c * 256 + tid, r = flat / SLOTS, s = flat % SLOTS;
      bv[c] = *(const uint4*)(W + (size_t)(n0 + r) * K + k0 + s * 8);
    }
  };
  auto writeT = [&](int buf) {
#pragma unroll
    for (int c = 0; c < A_IT; ++c) {
      int flat = c * 256 + tid, r = flat / SLOTS, s = flat % SLOTS;
      *(uint4*)(As[buf] + r * LDA + s * 8) = av[c];
    }
#pragma unroll
    for (int c = 0; c < B_IT; ++c) {
      int flat = c * 256 + tid, r = flat / SLOTS, s = flat % SLOTS;
      *(uint4*)(Bs[buf] + r * LDA + s * 8) = bv[c];
    }
  };

  f32x4 acc[MF][NF];
#pragma unroll
  for (int m = 0; m < MF; ++m)
#pragma unroll
    for (int n = 0; n < NF; ++n) {
      f32x4 z = {0.f, 0.f, 0.f, 0.f};
      acc[m][n] = z;
    }

  auto mma = [&](int buf) {
    const ushort* as = As[buf];
    const ushort* bs = Bs[buf];
#pragma unroll
    for (int ks = 0; ks < BK / 32; ++ks) {
      short8 af[MF], bf[NF];
#pragma unroll
      for (int m = 0; m < MF; ++m) {
        int r = wm * (BM / 2) + m * 16 + (lane & 15);
        af[m] = *(const short8*)(as + r * LDA + ks * 32 + (lane >> 4) * 8);
      }
#pragma unroll
      for (int n = 0; n < NF; ++n) {
        int cdx = wn * (BN / 2) + n * 16 + (lane & 15);
        bf[n] = *(const short8*)(bs + cdx * LDA + ks * 32 + (lane >> 4) * 8);
      }
#pragma unroll
      for (int m = 0; m < MF; ++m)
#pragma unroll
        for (int n = 0; n < NF; ++n)
          acc[m][n] = __builtin_amdgcn_mfma_f32_16x16x32_bf16(af[m], bf[n], acc[m][n], 0, 0, 0);
    }
  };

  loadT(0);
  writeT(0);
  __syncthreads();
  int cur = 0;
  for (int kt = 0; kt < NK; ++kt) {
    if (kt + 1 < NK) loadT(kt + 1);
    mma(cur);
    if (kt + 1 < NK) writeT(cur ^ 1);
    __syncthreads();
    cur ^= 1;
  }

  // C/D layout: col = lane&15, row = (lane>>4)*4 + reg   [m89-verified]
#pragma unroll
  for (int m = 0; m < MF; ++m)
#pragma unroll
    for (int n = 0; n < NF; ++n) {
      int colg = n0 + wn * (BN / 2) + n * 16 + (lane & 15);
      float bval = bias[colg];
#pragma unroll
      for (int r = 0; r < 4; ++r) {
        int rowg = m0 + wm * (BM / 2) + m * 16 + (lane >> 4) * 4 + r;
        float v = acc[m][n][r] + bval;
        if (RELU) v = fmaxf(v, 0.f);
        C[(size_t)rowg * N + colg] = f2bf(v);
      }
    }
}

// ---------------------------------------------------------------------------
// Fused GEMM2 + head: h2 = relu(h1 @ w2b^T + b2) in LDS, then
// logits = h2 @ W3^T + b3, log_softmax. BM=32, BN=128 (full N), dbuf K-loop.
// ---------------------------------------------------------------------------
__global__ __launch_bounds__(256) void gemm2_head(
    const ushort* __restrict__ h1, const ushort* __restrict__ w2b,
    const float* __restrict__ b2, const float* __restrict__ W3,
    const float* __restrict__ b3, float* __restrict__ out) {
  constexpr int LDA = 72;
  constexpr int NK = 4;   // K = 256, BK = 64
  __shared__ ushort As[2][32 * LDA];
  __shared__ ushort Bs[2][128 * LDA];
  __shared__ float h2f[32][132];
  __shared__ float W3s[1280];

  const int tid = threadIdx.x;
  const int lane = tid & 63;
  const int w = tid >> 6, wm = w >> 1, wn = w & 1;
  const int m0 = blockIdx.x * 32;

  for (int i = tid; i < 1280; i += 256) W3s[i] = W3[i];

  const int ar = tid >> 3, asl = tid & 7;

  uint4 av, bv[4];
  auto loadT = [&](int kt) {
    const int k0 = kt * 64;
    av = *(const uint4*)(h1 + (size_t)(m0 + ar) * 256 + k0 + asl * 8);
#pragma unroll
    for (int c = 0; c < 4; ++c) {
      int flat = c * 256 + tid, rb = flat >> 3, sb = flat & 7;
      bv[c] = *(const uint4*)(w2b + (size_t)rb * 256 + k0 + sb * 8);
    }
  };
  auto writeT = [&](int buf) {
    *(uint4*)(As[buf] + ar * LDA + asl * 8) = av;
#pragma unroll
    for (int c = 0; c < 4; ++c) {
      int flat = c * 256 + tid, rb = flat >> 3, sb = flat & 7;
      *(uint4*)(Bs[buf] + rb * LDA + sb * 8) = bv[c];
    }
  };

  f32x4 acc[4];
#pragma unroll
  for (int n = 0; n < 4; ++n) {
    f32x4 z = {0.f, 0.f, 0.f, 0.f};
    acc[n] = z;
  }

  auto mma = [&](int buf) {
    const ushort* as = As[buf];
    const ushort* bs = Bs[buf];
#pragma unroll
    for (int ks = 0; ks < 2; ++ks) {
      int r = wm * 16 + (lane & 15);
      short8 af = *(const short8*)(as + r * LDA + ks * 32 + (lane >> 4) * 8);
#pragma unroll
      for (int n = 0; n < 4; ++n) {
        int cdx = wn * 64 + n * 16 + (lane & 15);
        short8 bf = *(const short8*)(bs + cdx * LDA + ks * 32 + (lane >> 4) * 8);
        acc[n] = __builtin_amdgcn_mfma_f32_16x16x32_bf16(af, bf, acc[n], 0, 0, 0);
      }
    }
  };

  loadT(0);
  writeT(0);
  __syncthreads();
  int cur = 0;
  for (int kt = 0; kt < NK; ++kt) {
    if (kt + 1 < NK) loadT(kt + 1);
    mma(cur);
    if (kt + 1 < NK) writeT(cur ^ 1);
    __syncthreads();
    cur ^= 1;
  }

#pragma unroll
  for (int n = 0; n < 4; ++n) {
    int col = wn * 64 + n * 16 + (lane & 15);
    float bval = b2[col];
#pragma unroll
    for (int r = 0; r < 4; ++r)
      h2f[wm * 16 + (lane >> 4) * 4 + r][col] = fmaxf(acc[n][r] + bval, 0.f);
  }
  __syncthreads();

  {
    int r = tid >> 3, p = tid & 7;
    float a10[10];
#pragma unroll
    for (int n = 0; n < 10; ++n) a10[n] = 0.f;
#pragma unroll
    for (int e = 0; e < 16; ++e) {
      int k = e * 8 + p;
      float hv = h2f[r][k];
#pragma unroll
      for (int n = 0; n < 10; ++n) a10[n] = fmaf(hv, W3s[n * 128 + k], a10[n]);
    }
#pragma unroll
    for (int n = 0; n < 10; ++n) {
      a10[n] += __shfl_xor(a10[n], 1);
      a10[n] += __shfl_xor(a10[n], 2);
      a10[n] += __shfl_xor(a10[n], 4);
    }
    if (p == 0) {
#pragma unroll
      for (int n = 0; n < 10; ++n) a10[n] += b3[n];
      float mx = a10[0];
#pragma unroll
      for (int n = 1; n < 10; ++n) mx = fmaxf(mx, a10[n]);
      float s = 0.f;
#pragma unroll
      for (int n = 0; n < 10; ++n) s += __expf(a10[n] - mx);
      float lse = mx + __logf(s);
      float* po = out + (size_t)(m0 + r) * 10;
#pragma unroll
      for (int n = 0; n < 10; ++n) po[n] = a10[n] - lse;
    }
  }
}

// ---------------------------------------------------------------------------
extern "C" void kernel_launch(void* const* d_in, const int* in_sizes, int n_in,
                              void* d_out, int out_size, void* d_ws, size_t ws_size,
                              hipStream_t stream) {
  const float* x  = (const float*)d_in[0];   // (8192,1,28,28)
  // d_in[1] = params: provably unused (diagonal phases cancel in |amp|^2)
  const float* W1 = (const float*)d_in[2];
  const float* b1 = (const float*)d_in[3];
  const float* W2 = (const float*)d_in[4];
  const float* b2 = (const float*)d_in[5];
  const float* W3 = (const float*)d_in[6];
  const float* b3 = (const float*)d_in[7];
  float* out = (float*)d_out;

  char* ws = (char*)d_ws;
  ushort* feats = (ushort*)(ws);                      // 8192 x 832 bf16
  ushort* w1b   = (ushort*)(ws + 13631488);           // 256 x 832 bf16
  ushort* h1    = (ushort*)(ws + 14057472);           // 8192 x 256 bf16
  ushort* w2b   = (ushort*)(ws + 18251776);           // 128 x 256 bf16

  hipLaunchKernelGGL(feats_prep_kernel, dim3(7616), dim3(256), 0, stream,
                     x, feats, W1, W2, w1b, w2b);
  hipLaunchKernelGGL((gemm_bt_db<64, 64, 64, 8192, 256, 832, true>),
                     dim3((8192 / 64) * (256 / 64)), dim3(256), 0, stream,
                     feats, w1b, b1, h1);
  hipLaunchKernelGGL(gemm2_head, dim3(8192 / 32), dim3(256), 0, stream,
                     h1, w2b, b2, W3, b3, out);
}

// Round 6
// 33.043 us; speedup vs baseline: 1.6297x; 1.6297x over previous
//
#include <hip/hip_runtime.h>
#include <stdint.h>

typedef __attribute__((ext_vector_type(8))) short short8;
typedef __attribute__((ext_vector_type(4))) float f32x4;

#define DEVI __device__ __forceinline__

DEVI ushort f2bf(float f) {
  union { float f; uint32_t u; } v; v.f = f;
  uint32_t r = v.u + 0x7fffu + ((v.u >> 16) & 1u);
  return (ushort)(r >> 16);
}

DEVI ushort4 pack4(float a, float b, float c, float d) {
  ushort4 o; o.x = f2bf(a); o.y = f2bf(b); o.z = f2bf(c); o.w = f2bf(d);
  return o;
}

// ---------------------------------------------------------------------------
// Single-launch fully fused pipeline. Quantum circuit collapses analytically
// (params dead): feats per 2x2 patch = [cos v0, cos v1, cos v0*cos v2,
// cos v1*cos v3].
//
// Each block owns 32 batch rows end-to-end (BN = full 256), so there is no
// grid-wide dependency: feats cos computed exactly once chip-wide (rows
// partition); W1/W2 are re-read per block but fit XCD L2 (852/128 KB < 4 MB).
//   Phase 1: h1(32x256) = relu(feats(32x832) @ W1^T + b1) -> LDS bf16
//   Phase 2: h2(32x128) = relu(h1 @ W2^T + b2)            -> regs -> LDS f32
//   Phase 3: logits = h2 @ W3^T + b3; log_softmax         -> out
// 256 blocks x 512 threads (8 waves, 2/SIMD). Reg-prefetch + single-LDS-buf
// (2 barriers/K-step): global latency hides under MFMA.
// ---------------------------------------------------------------------------
#define LDB 72     // staging tile stride (ushort): 144B -> <=2-way banks
#define H1LD 280   // h1 tile stride (ushort): 560B, 16B-aligned, <=2-way

__global__ __launch_bounds__(512, 2) void mega_kernel(
    const float* __restrict__ x, const float* __restrict__ W1,
    const float* __restrict__ b1, const float* __restrict__ W2,
    const float* __restrict__ b2, const float* __restrict__ W3,
    const float* __restrict__ b3, float* __restrict__ out) {
  __shared__ __align__(16) ushort As[32 * LDB];     //  4608 B
  __shared__ __align__(16) ushort Bs[256 * LDB];    // 36864 B
  __shared__ __align__(16) ushort h1t[32 * H1LD];   // 17920 B (h2f overlays)
  __shared__ __align__(16) float W3s[1280];         //  5120 B   sum 64512

  const int tid = threadIdx.x;
  const int lane = tid & 63;
  const int w = tid >> 6;               // 8 waves, wave w covers cols w*32
  const int m0g = blockIdx.x * 32;      // global batch-row base

  // ---- staging thread mappings ----
  const int arow = tid >> 4, pl = tid & 15;      // A: 32 rows x 16 patches
  // B1: 256 rows x 16 float4-slots, 8 per thread (flat = c*512 + tid)

  // ---------------- Phase 1: h1 = relu(feats @ W1^T + b1) ----------------
  float2 xt, xb;                 // staged x (1 patch)
  bool aval;
  float4 bw[8];                  // staged W1 f32

  auto loadA1 = [&](int kt) {
    const int q = kt * 16 + pl;
    aval = (q < 196);
    if (aval) {
      const int i = q / 14, j = q - i * 14;
      const float* p = x + (size_t)(m0g + arow) * 784 + i * 56 + j * 2;
      xt = *(const float2*)p;
      xb = *(const float2*)(p + 28);
    }
  };
  auto loadB1 = [&](int kt) {
    const int k0 = kt * 64;
#pragma unroll
    for (int c = 0; c < 8; ++c) {
      const int flat = c * 512 + tid, r = flat >> 4, sl = flat & 15;
      if (k0 + sl * 4 < 784)
        bw[c] = *(const float4*)(W1 + (size_t)r * 784 + k0 + sl * 4);
      else
        bw[c] = make_float4(0.f, 0.f, 0.f, 0.f);
    }
  };
  auto writeT1 = [&]() {
    if (aval) {
      float c0 = __cosf(xt.x), c1 = __cosf(xt.y);
      float c2 = __cosf(xb.x), c3 = __cosf(xb.y);
      *(ushort4*)(As + arow * LDB + pl * 4) = pack4(c0, c1, c0 * c2, c1 * c3);
    } else {
      ushort4 z; z.x = 0; z.y = 0; z.z = 0; z.w = 0;
      *(ushort4*)(As + arow * LDB + pl * 4) = z;
    }
#pragma unroll
    for (int c = 0; c < 8; ++c) {
      const int flat = c * 512 + tid, r = flat >> 4, sl = flat & 15;
      *(ushort4*)(Bs + r * LDB + sl * 4) = pack4(bw[c].x, bw[c].y, bw[c].z, bw[c].w);
    }
  };

  f32x4 acc[2][2];               // wave tile 32 x 32 (MF=2, NF=2)
#pragma unroll
  for (int m = 0; m < 2; ++m)
#pragma unroll
    for (int n = 0; n < 2; ++n) {
      f32x4 z = {0.f, 0.f, 0.f, 0.f};
      acc[m][n] = z;
    }

  loadA1(0);
  loadB1(0);
  for (int kt = 0; kt < 13; ++kt) {
    writeT1();
    __syncthreads();
    if (kt < 12) { loadA1(kt + 1); loadB1(kt + 1); }   // prefetch (hidden)
#pragma unroll
    for (int ks = 0; ks < 2; ++ks) {
      short8 af[2], bf[2];
#pragma unroll
      for (int m = 0; m < 2; ++m)
        af[m] = *(const short8*)(As + (m * 16 + (lane & 15)) * LDB + ks * 32 + (lane >> 4) * 8);
#pragma unroll
      for (int n = 0; n < 2; ++n)
        bf[n] = *(const short8*)(Bs + (w * 32 + n * 16 + (lane & 15)) * LDB + ks * 32 + (lane >> 4) * 8);
#pragma unroll
      for (int m = 0; m < 2; ++m)
#pragma unroll
        for (int n = 0; n < 2; ++n)
          acc[m][n] = __builtin_amdgcn_mfma_f32_16x16x32_bf16(af[m], bf[n], acc[m][n], 0, 0, 0);
    }
    __syncthreads();
  }

  // epilogue: h1 tile -> LDS bf16 (bias+relu); also load W3 -> LDS
  // C/D layout: col = lane&15, row = (lane>>4)*4 + reg   [m89-verified]
#pragma unroll
  for (int n = 0; n < 2; ++n) {
    const int col = w * 32 + n * 16 + (lane & 15);
    const float bval = b1[col];
#pragma unroll
    for (int m = 0; m < 2; ++m)
#pragma unroll
      for (int r = 0; r < 4; ++r) {
        const int row = m * 16 + (lane >> 4) * 4 + r;
        h1t[row * H1LD + col] = f2bf(fmaxf(acc[m][n][r] + bval, 0.f));
      }
  }
  for (int i = tid; i < 1280; i += 512) W3s[i] = W3[i];
  __syncthreads();

  // ---------------- Phase 2: h2 = relu(h1 @ W2^T + b2) ----------------
  float4 bw2[4];                 // B2: 128 rows x 16 slots, 4 per thread
  auto loadB2 = [&](int kt) {
    const int k0 = kt * 64;
#pragma unroll
    for (int c = 0; c < 4; ++c) {
      const int flat = c * 512 + tid, r = flat >> 4, sl = flat & 15;
      bw2[c] = *(const float4*)(W2 + (size_t)r * 256 + k0 + sl * 4);
    }
  };
  auto writeT2 = [&]() {
#pragma unroll
    for (int c = 0; c < 4; ++c) {
      const int flat = c * 512 + tid, r = flat >> 4, sl = flat & 15;
      *(ushort4*)(Bs + r * LDB + sl * 4) = pack4(bw2[c].x, bw2[c].y, bw2[c].z, bw2[c].w);
    }
  };

  f32x4 acc2[2];                 // wave tile 32 x 16 (MF=2, NF=1), cols w*16
#pragma unroll
  for (int m = 0; m < 2; ++m) {
    f32x4 z = {0.f, 0.f, 0.f, 0.f};
    acc2[m] = z;
  }

  loadB2(0);
  for (int kt = 0; kt < 4; ++kt) {
    writeT2();
    __syncthreads();
    if (kt < 3) loadB2(kt + 1);
#pragma unroll
    for (int ks = 0; ks < 2; ++ks) {
      short8 bf = *(const short8*)(Bs + (w * 16 + (lane & 15)) * LDB + ks * 32 + (lane >> 4) * 8);
#pragma unroll
      for (int m = 0; m < 2; ++m) {
        short8 af = *(const short8*)(h1t + (m * 16 + (lane & 15)) * H1LD + kt * 64 + ks * 32 + (lane >> 4) * 8);
        acc2[m] = __builtin_amdgcn_mfma_f32_16x16x32_bf16(af, bf, acc2[m], 0, 0, 0);
      }
    }
    __syncthreads();
  }

  // h2 -> LDS f32 (overlays h1t; safe: loop ended with barrier)
  float* h2f = (float*)h1t;      // [32][132]
  {
    const int col = w * 16 + (lane & 15);
    const float bval = b2[col];
#pragma unroll
    for (int m = 0; m < 2; ++m)
#pragma unroll
      for (int r = 0; r < 4; ++r) {
        const int row = m * 16 + (lane >> 4) * 4 + r;
        h2f[row * 132 + col] = fmaxf(acc2[m][r] + bval, 0.f);
      }
  }
  __syncthreads();

  // ---------------- Phase 3: head (logits + log_softmax) ----------------
  {
    const int r = tid >> 4, p = tid & 15;   // 32 rows x 16 partials
    float a10[10];
#pragma unroll
    for (int n = 0; n < 10; ++n) a10[n] = 0.f;
#pragma unroll
    for (int e = 0; e < 8; ++e) {
      const int k = e * 16 + p;
      const float hv = h2f[r * 132 + k];
#pragma unroll
      for (int n = 0; n < 10; ++n) a10[n] = fmaf(hv, W3s[n * 128 + k], a10[n]);
    }
#pragma unroll
    for (int n = 0; n < 10; ++n) {
      a10[n] += __shfl_xor(a10[n], 1);
      a10[n] += __shfl_xor(a10[n], 2);
      a10[n] += __shfl_xor(a10[n], 4);
      a10[n] += __shfl_xor(a10[n], 8);
    }
    if (p == 0) {
#pragma unroll
      for (int n = 0; n < 10; ++n) a10[n] += b3[n];
      float mx = a10[0];
#pragma unroll
      for (int n = 1; n < 10; ++n) mx = fmaxf(mx, a10[n]);
      float s = 0.f;
#pragma unroll
      for (int n = 0; n < 10; ++n) s += __expf(a10[n] - mx);
      const float lse = mx + __logf(s);
      float* po = out + (size_t)(m0g + r) * 10;
#pragma unroll
      for (int n = 0; n < 10; ++n) po[n] = a10[n] - lse;
    }
  }
}

// ---------------------------------------------------------------------------
extern "C" void kernel_launch(void* const* d_in, const int* in_sizes, int n_in,
                              void* d_out, int out_size, void* d_ws, size_t ws_size,
                              hipStream_t stream) {
  const float* x  = (const float*)d_in[0];   // (8192,1,28,28)
  // d_in[1] = params: provably unused (diagonal phases cancel in |amp|^2)
  const float* W1 = (const float*)d_in[2];
  const float* b1 = (const float*)d_in[3];
  const float* W2 = (const float*)d_in[4];
  const float* b2 = (const float*)d_in[5];
  const float* W3 = (const float*)d_in[6];
  const float* b3 = (const float*)d_in[7];
  float* out = (float*)d_out;

  hipLaunchKernelGGL(mega_kernel, dim3(256), dim3(512), 0, stream,
                     x, W1, b1, W2, b2, W3, b3, out);
}